// Round 3
// baseline (238.896 us; speedup 1.0000x reference)
//
#include <hip/hip_runtime.h>
#include <hip/hip_cooperative_groups.h>

namespace coop = cooperative_groups;

#define B_     64
#define KDIM   2304
#define NCOL   1470
#define NCELL  3136   // 64 * 7 * 7
#define CPAD   1536
#define SPLITK 16
#define KCHUNK 144    // KDIM / SPLITK
#define NSTAGE 9      // KCHUNK / 16
#define NBLK   192    // 12 col-tiles * 16 K-chunks
#define NTHR   256
#define CPB    17     // cells per block: 192*17 = 3264 >= 3136

// Fused YOLOv1 head: GEMM -> sync -> combine+decode -> sync -> NMS+pack.
// LDS is a union across phases (max user: NMS ~40 KB).
__global__ __launch_bounds__(NTHR) void yolo_fused(
    const float* __restrict__ x, const float* __restrict__ W,
    const float* __restrict__ bias, float* __restrict__ out,
    float* __restrict__ partial, float* __restrict__ labels,
    float* __restrict__ boxes, float* __restrict__ scores,
    int* __restrict__ valid)
{
    __shared__ __align__(16) char smem[41600];
    const int t = threadIdx.x;
    const int b = blockIdx.x;
    coop::grid_group grid = coop::this_grid();

    // ============ Phase A: split-K GEMM (64x1470 = x @ W^T) ============
    {
        float* sx = (float*)smem;        // [16][68]  kk-major, row padded stride 68
        float* sw = sx + 16 * 68;        // [16][132] kk-major, col padded stride 132
        const int ct = b % 12;           // col-tile (128 cols)
        const int kc = b / 12;           // K-chunk
        const int c0 = ct * 128;
        const int k0 = kc * KCHUNK;
        const int r8 = (t >> 5) << 3;    // 8-row group
        const int cgi = t & 31;          // col group: cols cgi + {0,32,64,96}
        const int kk0 = t & 15;
        const int g0  = t >> 4;

        float acc[8][4];
#pragma unroll
        for (int i = 0; i < 8; ++i)
#pragma unroll
            for (int j = 0; j < 4; ++j) acc[i][j] = 0.f;

        float xr[4], wr[8];
        // prologue: load stage 0 into regs
        {
            const int kb = k0;
#pragma unroll
            for (int p = 0; p < 4; ++p)
                xr[p] = x[(p * 16 + g0) * KDIM + kb + kk0];
#pragma unroll
            for (int p = 0; p < 8; ++p) {
                int gc = c0 + p * 16 + g0;
                if (gc >= NCOL) gc = NCOL - 1;
                wr[p] = W[(size_t)gc * KDIM + kb + kk0];
            }
        }

        for (int s = 0; s < NSTAGE; ++s) {
            __syncthreads();               // prev compute done reading LDS
#pragma unroll
            for (int p = 0; p < 4; ++p) sx[kk0 * 68 + p * 16 + g0] = xr[p];
#pragma unroll
            for (int p = 0; p < 8; ++p) sw[kk0 * 132 + p * 16 + g0] = wr[p];
            __syncthreads();
            if (s + 1 < NSTAGE) {          // prefetch next stage (overlaps compute)
                const int kb = k0 + ((s + 1) << 4);
#pragma unroll
                for (int p = 0; p < 4; ++p)
                    xr[p] = x[(p * 16 + g0) * KDIM + kb + kk0];
#pragma unroll
                for (int p = 0; p < 8; ++p) {
                    int gc = c0 + p * 16 + g0;
                    if (gc >= NCOL) gc = NCOL - 1;
                    wr[p] = W[(size_t)gc * KDIM + kb + kk0];
                }
            }
#pragma unroll
            for (int kk = 0; kk < 16; ++kk) {
                const float4 a0 = *(const float4*)&sx[kk * 68 + r8];
                const float4 a1 = *(const float4*)&sx[kk * 68 + r8 + 4];
                const float w0 = sw[kk * 132 + cgi];
                const float w1 = sw[kk * 132 + cgi + 32];
                const float w2 = sw[kk * 132 + cgi + 64];
                const float w3 = sw[kk * 132 + cgi + 96];
                const float av[8] = {a0.x, a0.y, a0.z, a0.w, a1.x, a1.y, a1.z, a1.w};
#pragma unroll
                for (int i = 0; i < 8; ++i) {
                    acc[i][0] = fmaf(av[i], w0, acc[i][0]);
                    acc[i][1] = fmaf(av[i], w1, acc[i][1]);
                    acc[i][2] = fmaf(av[i], w2, acc[i][2]);
                    acc[i][3] = fmaf(av[i], w3, acc[i][3]);
                }
            }
        }
        float* pb = partial + (size_t)kc * (B_ * CPAD) + c0 + cgi;
#pragma unroll
        for (int i = 0; i < 8; ++i)
#pragma unroll
            for (int p = 0; p < 4; ++p)
                pb[(size_t)(r8 + i) * CPAD + 32 * p] = acc[i][p];
    }

    grid.sync();

    // ============ Phase B: combine split-K + bias + per-cell decode ============
    {
        float (*sa)[30] = (float(*)[30])smem;     // 17 cells x 30 cols
        const int start = b * CPB;
        for (int lc = t; lc < CPB * 30; lc += NTHR) {
            const int cell = lc / 30;
            const int n = start + cell;
            if (n < NCELL) {
                const int col = lc % 30;
                const int row = n / 49;                 // 1470/30 = 49 cells/row
                const int cr  = (n % 49) * 30 + col;
                float s = 0.f;
#pragma unroll
                for (int k = 0; k < SPLITK; ++k)
                    s += partial[(size_t)k * (B_ * CPAD) + (size_t)row * CPAD + cr];
                s += bias[cr];
                sa[cell][col] = s;
                if (col >= 10) labels[(size_t)n * 20 + (col - 10)] = s;
            }
        }
        __syncthreads();
        if (t < CPB && start + t < NCELL) {
            const int n = start + t;
            const float* a = sa[t];
            float mv = a[10]; int mi = 0;
#pragma unroll
            for (int j = 1; j < 20; ++j) {
                float v = a[10 + j];
                if (v > mv) { mv = v; mi = j; }          // first-index tie-break
            }
            const float lp = (float)mi;
            const int gx = n % 7, gy = (n / 7) % 7;
            const float cw = 1.0f / 7.0f;
            const float nx = (float)gx * cw, ny = (float)gy * cw;
#pragma unroll
            for (int sl = 0; sl < 2; ++sl) {
                const int off = 5 * sl;
                const float bx0 = a[off], bx1 = a[off + 1];
                const float w_ = a[off + 2], h_ = a[off + 3];
                const float sc = a[off + 5];             // faithful port quirk
                const float cx = bx0 * cw + nx, cy = bx1 * cw + ny;
                const float X1 = cx - 0.5f * w_, Y1 = cy - 0.5f * h_;
                const float X2 = cx + 0.5f * w_, Y2 = cy + 0.5f * h_;
                const int m = sl * NCELL + n;
                boxes[m * 4 + 0] = X1 - 0.5f * X2;
                boxes[m * 4 + 1] = Y1 - 0.5f * Y2;
                boxes[m * 4 + 2] = X1 + 0.5f * X2;
                boxes[m * 4 + 3] = Y1 + 0.5f * Y2;
                scores[m] = sc;
                valid[m] = (sc * lp > 0.5f) ? 1 : 0;
            }
        }
    }

    grid.sync();

    if (b >= 2) return;   // no more grid barriers below

    // ============ Phase C: inverted greedy NMS + pack (block b = slot b) ======
    {
        int*   lstA = (int*)smem;                          // 3136
        int*   lstB = lstA + NCELL;                        // 3136
        float* ssc  = (float*)(lstB + NCELL);              // 3136
        unsigned char* keepSh = (unsigned char*)(ssc + NCELL);  // 3136 B
        int*   misc = (int*)(keepSh + NCELL);              // 4-aligned (offset 40768)
        float* rv = (float*)(misc + 4);                    // 4
        int*   ri = (int*)(rv + 4);                        // 4
#define CNT_A misc[0]
#define CNT_B misc[1]
#define SPICK misc[2]

        const int base = b * NCELL;
        if (t == 0) { CNT_A = 0; CNT_B = 0; }
        __syncthreads();
        for (int n = t; n < NCELL; n += NTHR) {
            ssc[n] = scores[base + n];
            keepSh[n] = 0;
            if (valid[base + n]) { int p = atomicAdd(&CNT_A, 1); lstA[p] = n; }
        }
        __syncthreads();

        int* cur = lstA; int* nxt = lstB;
        int curIsA = 1;
        for (;;) {
            const int cnt = curIsA ? CNT_A : CNT_B;
            // argmax over alive (first/min index wins ties)
            float bv = -1e30f; int bi = 0x7fffffff;
            for (int j = t; j < cnt; j += NTHR) {
                const int n = cur[j];
                const float v = ssc[n];
                if (v > bv || (v == bv && n < bi)) { bv = v; bi = n; }
            }
#pragma unroll
            for (int o = 32; o > 0; o >>= 1) {
                const float ov = __shfl_down(bv, o);
                const int   oi = __shfl_down(bi, o);
                if (ov > bv || (ov == bv && oi < bi)) { bv = ov; bi = oi; }
            }
            if ((t & 63) == 0) { rv[t >> 6] = bv; ri[t >> 6] = bi; }
            __syncthreads();
            if (t == 0) {
                float v2 = rv[0]; int i2 = ri[0];
#pragma unroll
                for (int q = 1; q < 4; ++q)
                    if (rv[q] > v2 || (rv[q] == v2 && ri[q] < i2)) { v2 = rv[q]; i2 = ri[q]; }
                SPICK = (v2 == -1e30f) ? -1 : i2;
                if (curIsA) CNT_B = 0; else CNT_A = 0;
            }
            __syncthreads();
            const int i = SPICK;
            if (i < 0) break;
            if (t == 0) keepSh[i] = 1;

            const float xi1 = boxes[(size_t)(base + i) * 4 + 0];
            const float yi1 = boxes[(size_t)(base + i) * 4 + 1];
            const float xi2 = boxes[(size_t)(base + i) * 4 + 2];
            const float yi2 = boxes[(size_t)(base + i) * 4 + 3];
            const float ai  = (xi2 - xi1) * (yi2 - yi1);

            int* nxtCnt = curIsA ? &CNT_B : &CNT_A;
            for (int j = t; j < cnt; j += NTHR) {
                const int n = cur[j];
                const float x1 = boxes[(size_t)(base + n) * 4 + 0];
                const float y1 = boxes[(size_t)(base + n) * 4 + 1];
                const float x2 = boxes[(size_t)(base + n) * 4 + 2];
                const float y2 = boxes[(size_t)(base + n) * 4 + 3];
                const float an = (x2 - x1) * (y2 - y1);
                const float ix1 = fmaxf(x1, xi1), iy1 = fmaxf(y1, yi1);
                const float ix2 = fminf(x2, xi2), iy2 = fminf(y2, yi2);
                const float inter = fmaxf(ix2 - ix1, 0.f) * fmaxf(iy2 - iy1, 0.f);
                const float iou = inter / (ai + an - inter);   // IEEE divide
                if (iou >= 0.5f && n != i) { int p = atomicAdd(nxtCnt, 1); nxt[p] = n; }
            }
            __syncthreads();
            { int* tmp = cur; cur = nxt; nxt = tmp; }
            curIsA ^= 1;
        }

        // pack this slot: out[sn][c] = {boxes*448, score, labels} * keep
        for (int li = t; li < NCELL * 25; li += NTHR) {
            const int n = li / 25;
            const int c = li % 25;
            const int sn = base + n;
            const float k = (float)keepSh[n];
            float v;
            if (c < 4)       v = boxes[(size_t)sn * 4 + c] * 448.0f;
            else if (c == 4) v = ssc[n];
            else             v = labels[(size_t)n * 20 + (c - 5)];
            out[(size_t)base * 25 + li] = v * k;
        }
#undef CNT_A
#undef CNT_B
#undef SPICK
    }
}

// ---------------------------------------------------------------------------
extern "C" void kernel_launch(void* const* d_in, const int* in_sizes, int n_in,
                              void* d_out, int out_size, void* d_ws, size_t ws_size,
                              hipStream_t stream)
{
    const float* x = (const float*)d_in[0];
    const float* W = (const float*)d_in[1];
    const float* b = (const float*)d_in[2];
    float* out = (float*)d_out;

    float* ws      = (float*)d_ws;
    float* partial = ws;                                        // 16*64*1536
    float* labels  = partial + (size_t)SPLITK * B_ * CPAD;      // 3136*20
    float* boxes   = labels + (size_t)NCELL * 20;               // 3136*8
    float* scores  = boxes + (size_t)NCELL * 8;                 // 3136*2
    int*   valid   = (int*)(scores + (size_t)NCELL * 2);        // 3136*2

    void* args[] = {(void*)&x, (void*)&W, (void*)&b, (void*)&out,
                    (void*)&partial, (void*)&labels, (void*)&boxes,
                    (void*)&scores, (void*)&valid};
    hipLaunchCooperativeKernel((const void*)yolo_fused, dim3(NBLK), dim3(NTHR),
                               args, 0, stream);
}

// Round 4
// 34.123 us; speedup vs baseline: 7.0010x; 7.0010x over previous
//
#include <hip/hip_runtime.h>

#define B_     64
#define KDIM   2304
#define NCOL   1470
#define NCELL  3136   // 64 * 7 * 7
#define CPAD   1536
#define SPLITK 16
#define KCHUNK 144    // KDIM / SPLITK
#define NSTAGE 9      // KCHUNK / 16

// ---------------------------------------------------------------------------
// GEMM: partial[kc][row][col] = sum_{k in chunk} x[row][k] * W[col][k]
// Grid (16 col-tiles of 96, 16 K-chunks) = 256 blocks = 1 per CU.
// Block 256. Micro-tile 8 rows x 3 cols (cols strided by 32: conflict-free).
// Register prefetch double-buffers the global->LDS staging.
// ---------------------------------------------------------------------------
__global__ __launch_bounds__(256) void gemm_splitk(
    const float* __restrict__ x, const float* __restrict__ W,
    float* __restrict__ partial)
{
    __shared__ float sx[16 * 68];    // [kk][row], stride 68: writes 2-way(free), reads broadcast
    __shared__ float sw[16 * 100];   // [kk][col], stride 100: writes 2-way(free), reads conflict-free

    const int t   = threadIdx.x;
    const int c0  = blockIdx.x * 96;
    const int k0  = blockIdx.y * KCHUNK;
    const int r8  = (t >> 5) << 3;   // 8-row group: 0,8,...,56
    const int cgi = t & 31;          // cols cgi + {0,32,64}
    const int kk0 = t & 15;
    const int g0  = t >> 4;          // 0..15

    float acc[8][3];
#pragma unroll
    for (int i = 0; i < 8; ++i)
#pragma unroll
        for (int j = 0; j < 3; ++j) acc[i][j] = 0.f;

    float xr[4], wr[6];
    {   // prologue: stage 0 into regs
        const int kb = k0;
#pragma unroll
        for (int p = 0; p < 4; ++p)
            xr[p] = x[(p * 16 + g0) * KDIM + kb + kk0];
#pragma unroll
        for (int p = 0; p < 6; ++p) {
            int gc = c0 + p * 16 + g0;
            if (gc >= NCOL) gc = NCOL - 1;       // clamp; garbage cols ignored downstream
            wr[p] = W[(size_t)gc * KDIM + kb + kk0];
        }
    }

    for (int s = 0; s < NSTAGE; ++s) {
        __syncthreads();                          // prev compute done with LDS
#pragma unroll
        for (int p = 0; p < 4; ++p) sx[kk0 * 68 + p * 16 + g0] = xr[p];
#pragma unroll
        for (int p = 0; p < 6; ++p) sw[kk0 * 100 + p * 16 + g0] = wr[p];
        __syncthreads();
        if (s + 1 < NSTAGE) {                     // prefetch next stage under compute
            const int kb = k0 + ((s + 1) << 4);
#pragma unroll
            for (int p = 0; p < 4; ++p)
                xr[p] = x[(p * 16 + g0) * KDIM + kb + kk0];
#pragma unroll
            for (int p = 0; p < 6; ++p) {
                int gc = c0 + p * 16 + g0;
                if (gc >= NCOL) gc = NCOL - 1;
                wr[p] = W[(size_t)gc * KDIM + kb + kk0];
            }
        }
#pragma unroll
        for (int kk = 0; kk < 16; ++kk) {
            const float4 a0 = *(const float4*)&sx[kk * 68 + r8];
            const float4 a1 = *(const float4*)&sx[kk * 68 + r8 + 4];
            const float w0 = sw[kk * 100 + cgi];
            const float w1 = sw[kk * 100 + cgi + 32];
            const float w2 = sw[kk * 100 + cgi + 64];
            const float av[8] = {a0.x, a0.y, a0.z, a0.w, a1.x, a1.y, a1.z, a1.w};
#pragma unroll
            for (int i = 0; i < 8; ++i) {
                acc[i][0] = fmaf(av[i], w0, acc[i][0]);
                acc[i][1] = fmaf(av[i], w1, acc[i][1]);
                acc[i][2] = fmaf(av[i], w2, acc[i][2]);
            }
        }
    }

    float* pb = partial + (size_t)blockIdx.y * (B_ * CPAD) + c0 + cgi;
#pragma unroll
    for (int i = 0; i < 8; ++i)
#pragma unroll
        for (int p = 0; p < 3; ++p)
            pb[(size_t)(r8 + i) * CPAD + 32 * p] = acc[i][p];
}

// ---------------------------------------------------------------------------
// Fused split-K combine + bias + per-cell decode (8 cells per 256-thr block).
// ---------------------------------------------------------------------------
__global__ __launch_bounds__(256) void combine_prep(
    const float* __restrict__ partial, const float* __restrict__ bias,
    float* __restrict__ labels, float* __restrict__ boxes,
    float* __restrict__ scores, int* __restrict__ valid)
{
    __shared__ float sa[8][30];
    const int t    = threadIdx.x;
    const int base = blockIdx.x * 8;             // 392 * 8 == 3136 exactly

    if (t < 240) {
        const int n   = base + t / 30;
        const int col = t % 30;
        const int row = n / 49;                  // 1470/30 = 49 cells per batch-row
        const int cr  = (n % 49) * 30 + col;
        float s = 0.f;
#pragma unroll
        for (int k = 0; k < SPLITK; ++k)
            s += partial[(size_t)k * (B_ * CPAD) + (size_t)row * CPAD + cr];
        s += bias[cr];
        sa[t / 30][col] = s;
        if (col >= 10) labels[(size_t)n * 20 + (col - 10)] = s;
    }
    __syncthreads();

    if (t < 8) {
        const int n = base + t;
        const float* a = sa[t];
        float mv = a[10]; int mi = 0;
#pragma unroll
        for (int j = 1; j < 20; ++j) {
            float v = a[10 + j];
            if (v > mv) { mv = v; mi = j; }      // strict > => first-index tie-break
        }
        const float lp = (float)mi;
        const int gx = n % 7, gy = (n / 7) % 7;
        const float cw = 1.0f / 7.0f;
        const float nx = (float)gx * cw, ny = (float)gy * cw;
#pragma unroll
        for (int sl = 0; sl < 2; ++sl) {
            const int off = 5 * sl;
            const float bx0 = a[off], bx1 = a[off + 1];
            const float w_ = a[off + 2], h_ = a[off + 3];
            const float sc = a[off + 5];         // faithful port quirk: off+5
            const float cx = bx0 * cw + nx, cy = bx1 * cw + ny;
            const float X1 = cx - 0.5f * w_, Y1 = cy - 0.5f * h_;
            const float X2 = cx + 0.5f * w_, Y2 = cy + 0.5f * h_;
            const int m = sl * NCELL + n;
            boxes[m * 4 + 0] = X1 - 0.5f * X2;
            boxes[m * 4 + 1] = Y1 - 0.5f * Y2;
            boxes[m * 4 + 2] = X1 + 0.5f * X2;
            boxes[m * 4 + 3] = Y1 + 0.5f * Y2;
            scores[m] = sc;
            valid[m] = (sc * lp > 0.5f) ? 1 : 0;
        }
    }
}

// ---------------------------------------------------------------------------
// Inverted greedy NMS, all data in LDS (boxes SoA + scores + lists ~91 KB).
// One 1024-thread block per slot. Compacted alive lists; 3 barriers/iter.
// ---------------------------------------------------------------------------
__global__ __launch_bounds__(1024) void nms_kernel(
    const float* __restrict__ boxes, const float* __restrict__ scores,
    const int* __restrict__ valid, float* __restrict__ keep)
{
    __shared__ float bx1[NCELL], by1[NCELL], bx2[NCELL], by2[NCELL];
    __shared__ float ssc[NCELL];
    __shared__ int   lstA[NCELL], lstB[NCELL];
    __shared__ unsigned char kp[NCELL];
    __shared__ float rv[16];
    __shared__ int   ri[16];
    __shared__ int   cA, cB, spick;

    const int slot = blockIdx.x;
    const int base = slot * NCELL;
    const int t = threadIdx.x;

    if (t == 0) { cA = 0; cB = 0; }
    __syncthreads();
    for (int n = t; n < NCELL; n += 1024) {
        const float4 bb = *(const float4*)&boxes[(size_t)(base + n) * 4];
        bx1[n] = bb.x; by1[n] = bb.y; bx2[n] = bb.z; by2[n] = bb.w;
        ssc[n] = scores[base + n];
        kp[n] = 0;
        if (valid[base + n]) { int p = atomicAdd(&cA, 1); lstA[p] = n; }
    }
    __syncthreads();

    int* cur = lstA; int* nxt = lstB;
    int curIsA = 1;
    for (;;) {
        const int cnt = curIsA ? cA : cB;

        // ---- argmax over alive (first/min index wins ties) ----
        float bv = -1e30f; int bi = 0x7fffffff;
        for (int j = t; j < cnt; j += 1024) {
            const int n = cur[j];
            const float v = ssc[n];
            if (v > bv || (v == bv && n < bi)) { bv = v; bi = n; }
        }
#pragma unroll
        for (int o = 32; o > 0; o >>= 1) {
            const float ov = __shfl_down(bv, o);
            const int   oi = __shfl_down(bi, o);
            if (ov > bv || (ov == bv && oi < bi)) { bv = ov; bi = oi; }
        }
        if ((t & 63) == 0) { rv[t >> 6] = bv; ri[t >> 6] = bi; }
        __syncthreads();
        if (t == 0) {
            float v2 = rv[0]; int i2 = ri[0];
#pragma unroll
            for (int q = 1; q < 16; ++q)
                if (rv[q] > v2 || (rv[q] == v2 && ri[q] < i2)) { v2 = rv[q]; i2 = ri[q]; }
            spick = (v2 == -1e30f) ? -1 : i2;
            if (curIsA) cB = 0; else cA = 0;
        }
        __syncthreads();
        const int i = spick;
        if (i < 0) break;
        if (t == 0) kp[i] = 1;

        const float xi1 = bx1[i], yi1 = by1[i], xi2 = bx2[i], yi2 = by2[i];
        const float ai  = (xi2 - xi1) * (yi2 - yi1);

        int* nxtCnt = curIsA ? &cB : &cA;
        for (int j = t; j < cnt; j += 1024) {
            const int n = cur[j];
            const float x1 = bx1[n], y1 = by1[n], x2 = bx2[n], y2 = by2[n];
            const float an = (x2 - x1) * (y2 - y1);
            const float ix1 = fmaxf(x1, xi1), iy1 = fmaxf(y1, yi1);
            const float ix2 = fminf(x2, xi2), iy2 = fminf(y2, yi2);
            const float inter = fmaxf(ix2 - ix1, 0.f) * fmaxf(iy2 - iy1, 0.f);
            const float iou = inter / (ai + an - inter);   // IEEE divide, as reference
            if (iou >= 0.5f && n != i) { int p = atomicAdd(nxtCnt, 1); nxt[p] = n; }
        }
        __syncthreads();
        { int* tmp = cur; cur = nxt; nxt = tmp; }
        curIsA ^= 1;
    }

    for (int n = t; n < NCELL; n += 1024)
        keep[base + n] = (float)kp[n];
}

// ---------------------------------------------------------------------------
// Pack output: (2, 3136, 25) = [boxes*448, score, labels(20)] * keep
// ---------------------------------------------------------------------------
__global__ void pack_out(const float* __restrict__ labels,
                         const float* __restrict__ boxes,
                         const float* __restrict__ scores,
                         const float* __restrict__ keep,
                         float* __restrict__ out)
{
    int idx = blockIdx.x * 256 + threadIdx.x;
    if (idx >= 2 * NCELL * 25) return;
    int c  = idx % 25;
    int sn = idx / 25;           // s*NCELL + n
    int n  = sn % NCELL;
    float k = keep[sn];
    float v;
    if (c < 4)       v = boxes[(size_t)sn * 4 + c] * 448.0f;
    else if (c == 4) v = scores[sn];
    else             v = labels[(size_t)n * 20 + (c - 5)];
    out[idx] = v * k;
}

// ---------------------------------------------------------------------------
extern "C" void kernel_launch(void* const* d_in, const int* in_sizes, int n_in,
                              void* d_out, int out_size, void* d_ws, size_t ws_size,
                              hipStream_t stream)
{
    const float* x = (const float*)d_in[0];
    const float* W = (const float*)d_in[1];
    const float* b = (const float*)d_in[2];
    float* out = (float*)d_out;

    float* ws      = (float*)d_ws;
    float* partial = ws;                                        // 16*64*1536
    float* labels  = partial + (size_t)SPLITK * B_ * CPAD;      // 3136*20
    float* boxes   = labels + (size_t)NCELL * 20;               // 3136*8
    float* scores  = boxes + (size_t)NCELL * 8;                 // 3136*2
    int*   valid   = (int*)(scores + (size_t)NCELL * 2);        // 3136*2
    float* keep    = (float*)(valid + (size_t)NCELL * 2);       // 3136*2

    hipLaunchKernelGGL(gemm_splitk, dim3(16, SPLITK), dim3(256), 0, stream,
                       x, W, partial);
    hipLaunchKernelGGL(combine_prep, dim3(NCELL / 8), dim3(256), 0, stream,
                       partial, b, labels, boxes, scores, valid);
    hipLaunchKernelGGL(nms_kernel, dim3(2), dim3(1024), 0, stream,
                       boxes, scores, valid, keep);
    hipLaunchKernelGGL(pack_out, dim3((2 * NCELL * 25 + 255) / 256), dim3(256), 0, stream,
                       labels, boxes, scores, keep, out);
}